// Round 3
// baseline (17985.497 us; speedup 1.0000x reference)
//
#include <hip/hip_runtime.h>
#include <math.h>
#include <string.h>

// ---------------- dims ----------------
#define B_ 32
#define C_ 3
#define HW_ 224
#define NP_ 14
#define PS_ 16
#define S_ 197        // NP*NP + 1
#define D_ 768
#define NH_ 12
#define DH_ 64
#define L_ 12
#define MLP_ 3072
#define OUT_ 1000
#define SP_ 224       // S padded to mult of 32

typedef unsigned short u16;
typedef unsigned int u32;
typedef __attribute__((ext_vector_type(8))) short short8_t;
typedef __attribute__((ext_vector_type(4))) float f32x4;
typedef const __attribute__((address_space(1))) u16 gq_t;
typedef __attribute__((address_space(3))) u16 lq_t;

// ---------------- bf16 helpers ----------------
__device__ __forceinline__ u16 f2bf(float x) {
    union { float f; u32 u; } a; a.f = x;
    u32 r = (a.u + 0x7fffu + ((a.u >> 16) & 1u)) >> 16;   // RNE
    return (u16)r;
}
__device__ __forceinline__ float bf2f(u16 h) {
    union { u32 u; float f; } a; a.u = ((u32)h) << 16; return a.f;
}

// ================= universal bf16x3 split MFMA GEMM =================
struct GP {
    const u16 *Ahi, *Alo, *Bhi, *Blo;
    long long sA, sB;          // batch strides (elements)
    int lda, ldb, M, N, K;
    int MB, SW;                // m-blocks, swizzle stripe width (n-blocks)
    int mode;                  // 0: fp32 out, 1: gelu->hi/lo, 2: qkv scatter
    float* C; const float* bias; long long sCo, sCi; int zdiv, ldc, accum, atomicf, remap, biasZ0;
    u16 *Ohi, *Olo; int ldo;
    u16 *qh, *ql, *kh, *kl, *vh, *vl; const float *bq, *bk, *bv;
};

template<int WN>   // WN: waves along N (2 -> 128x128 tile/256t, 1 -> 128x64/128t)
__global__ __launch_bounds__(WN * 128) void gm(GP p)
{
    const int TN = 64 * WN;
    __shared__ u16 ldsA[2][2][4][128][8];   // [buf][hi/lo][k-octet][row][8]
    __shared__ u16 ldsB[2][2][4][TN][8];

    int tid = threadIdx.x;
    int lane = tid & 63;
    int w = tid >> 6;
    int wm, wn;
    if (WN == 2) { wm = (w >> 1) * 64; wn = (w & 1) * 64; }
    else         { wm = w * 64;        wn = 0; }
    int z = blockIdx.y;

    // swizzle: m-major stripes of SW n-blocks (L2 locality for B panels)
    int lin = blockIdx.x;
    int stripe = lin / (p.SW * p.MB);
    int within = lin % (p.SW * p.MB);
    int bn = stripe * p.SW + within % p.SW;
    int bm = within / p.SW;
    int m0 = bm * 128, n0 = bn * TN;

    const u16* Ah = p.Ahi + (long long)z * p.sA;
    const u16* Al = p.Alo + (long long)z * p.sA;
    const u16* Bh = p.Bhi + (long long)z * p.sB;
    const u16* Bl = p.Blo + (long long)z * p.sB;

    int lm = lane & 15, qd = lane >> 4;

    const int nA = 16;
    const int nB = 8 * WN;
    const int W = 2 * WN;
    const int perW = (nA + nB) / W;

    auto stage = [&](int buf, int k0) {
#pragma unroll
        for (int t0 = 0; t0 < perW; ++t0) {
            int t = w * perW + t0;
            const u16* src; u16* dst;
            if (t < nA) {
                int mat = t >> 3, rem = t & 7, q = rem >> 1, h = rem & 1;
                int r = m0 + h * 64 + lane;
                r = r < p.M ? r : p.M - 1;
                src = (mat ? Al : Ah) + (long long)r * p.lda + (k0 + q * 8);
                dst = &ldsA[buf][mat][q][h * 64 + lane][0];
            } else {
                int tb = t - nA, mat, q, h;
                if (WN == 2) { mat = tb >> 3; int rem = tb & 7; q = rem >> 1; h = rem & 1; }
                else         { mat = tb >> 2; q = tb & 3; h = 0; }
                int r = n0 + h * 64 + lane;
                r = r < p.N ? r : p.N - 1;
                src = (mat ? Bl : Bh) + (long long)r * p.ldb + (k0 + q * 8);
                dst = &ldsB[buf][mat][q][h * 64 + lane][0];
            }
            __builtin_amdgcn_global_load_lds((gq_t*)src, (lq_t*)dst, 16, 0, 0);
        }
    };

    f32x4 acc[4][4];
#pragma unroll
    for (int i = 0; i < 4; ++i)
#pragma unroll
        for (int j = 0; j < 4; ++j)
            acc[i][j] = (f32x4){0.f, 0.f, 0.f, 0.f};

    int nc = p.K >> 5;
    stage(0, 0);
    for (int c = 0; c < nc; ++c) {
        __syncthreads();                       // drains loads into buf c&1
        if (c + 1 < nc) stage((c + 1) & 1, (c + 1) * 32);
        int buf = c & 1;
        short8_t ah[4], al[4], bh[4], bl[4];
#pragma unroll
        for (int i = 0; i < 4; ++i) {
            ah[i] = *(const short8_t*)&ldsA[buf][0][qd][wm + i * 16 + lm][0];
            al[i] = *(const short8_t*)&ldsA[buf][1][qd][wm + i * 16 + lm][0];
            bh[i] = *(const short8_t*)&ldsB[buf][0][qd][wn + i * 16 + lm][0];
            bl[i] = *(const short8_t*)&ldsB[buf][1][qd][wn + i * 16 + lm][0];
        }
#pragma unroll
        for (int i = 0; i < 4; ++i)
#pragma unroll
            for (int j = 0; j < 4; ++j) {
                acc[i][j] = __builtin_amdgcn_mfma_f32_16x16x32_bf16(ah[i], bh[j], acc[i][j], 0, 0, 0);
                acc[i][j] = __builtin_amdgcn_mfma_f32_16x16x32_bf16(ah[i], bl[j], acc[i][j], 0, 0, 0);
                acc[i][j] = __builtin_amdgcn_mfma_f32_16x16x32_bf16(al[i], bh[j], acc[i][j], 0, 0, 0);
            }
    }

    // ---- epilogue: C/D layout col=lane&15, row=quad*4+reg ----
#pragma unroll
    for (int j = 0; j < 4; ++j) {
        int gn = n0 + wn + j * 16 + lm;
        if (gn >= p.N) continue;
#pragma unroll
        for (int i = 0; i < 4; ++i) {
#pragma unroll
            for (int r = 0; r < 4; ++r) {
                int gm = m0 + wm + i * 16 + qd * 4 + r;
                if (gm >= p.M) continue;
                float v = acc[i][j][r];
                if (p.mode == 0) {
                    if (p.bias && (!p.biasZ0 || z == 0)) v += p.bias[gn];
                    int orow = p.remap ? (gm + gm / 196 + 1) : gm;
                    long long idx = (long long)(z / p.zdiv) * p.sCo + (long long)(z % p.zdiv) * p.sCi
                                  + (long long)orow * p.ldc + gn;
                    if (p.atomicf) atomicAdd(&p.C[idx], v);
                    else { if (p.accum) v += p.C[idx]; p.C[idx] = v; }
                } else if (p.mode == 1) {
                    v += p.bias[gn];
                    v = 0.5f * v * (1.0f + erff(v * 0.70710678118654752f));
                    u16 h = f2bf(v);
                    long long idx = (long long)gm * p.ldo + gn;
                    p.Ohi[idx] = h;
                    p.Olo[idx] = f2bf(v - bf2f(h));
                } else {
                    int b = gm / S_, s = gm - b * S_;
                    if (gn < 64) {
                        float val = (v + p.bq[z * 64 + gn]) * 0.125f;
                        long long idx = ((long long)(b * NH_ + z) * S_ + s) * 64 + gn;
                        u16 h = f2bf(val);
                        p.qh[idx] = h; p.ql[idx] = f2bf(val - bf2f(h));
                    } else if (gn < 128) {
                        int e = gn - 64;
                        float val = v + p.bk[z * 64 + e];
                        long long idx = ((long long)(b * NH_ + z) * S_ + s) * 64 + e;
                        u16 h = f2bf(val);
                        p.kh[idx] = h; p.kl[idx] = f2bf(val - bf2f(h));
                    } else {
                        int e = gn - 128;
                        float val = v + p.bv[z * 64 + e];
                        long long idx = ((long long)(b * NH_ + z) * 64 + e) * SP_ + s;
                        u16 h = f2bf(val);
                        p.vh[idx] = h; p.vl[idx] = f2bf(val - bf2f(h));
                    }
                }
            }
        }
    }
}

// ---------------- transpose + hi/lo split: W[K][N] -> T[N][K] ----------------
__global__ __launch_bounds__(256) void tconv_kernel(const float* __restrict__ W,
                                                    u16* __restrict__ Thi, u16* __restrict__ Tlo,
                                                    int K, int N)
{
    __shared__ float t[32][33];
    int n0 = blockIdx.x * 32, k0 = blockIdx.y * 32;
    int tc = threadIdx.x & 31, tr = threadIdx.x >> 5;
#pragma unroll
    for (int u = 0; u < 4; ++u) {
        int kk = tr + u * 8;
        t[kk][tc] = W[(long long)(k0 + kk) * N + n0 + tc];
    }
    __syncthreads();
#pragma unroll
    for (int u = 0; u < 4; ++u) {
        int nn = tr + u * 8;
        float v = t[tc][nn];
        u16 h = f2bf(v);
        long long idx = (long long)(n0 + nn) * K + k0 + tc;
        Thi[idx] = h;
        Tlo[idx] = f2bf(v - bf2f(h));
    }
}

// ---------------- QKV weight prep: Wcat[l][h][p*64+e][d] = w_p[l][h][d][e] ----
__global__ void qkvprep_kernel(const float* __restrict__ wq, const float* __restrict__ wk,
                               const float* __restrict__ wv,
                               u16* __restrict__ Whi, u16* __restrict__ Wlo) {
    int idx = blockIdx.x * 256 + threadIdx.x;
    const int TOT = L_ * NH_ * 192 * 64;
    if (idx >= TOT) return;
    int d = idx & 63;
    int r = (idx >> 6) % 192;
    int h = (idx >> 6) / 192 % NH_;
    int l = idx / (192 * 64 * NH_);
    int pg = r >> 6, e = r & 63;
    const float* W = pg == 0 ? wq : pg == 1 ? wk : wv;
    float v = W[(((long long)l * NH_ + h) * 64 + d) * 64 + e];
    u16 hh = f2bf(v);
    Whi[idx] = hh;
    Wlo[idx] = f2bf(v - bf2f(hh));
}

// ---------------- zero fill ----------------
__global__ void zero_kernel(u32* __restrict__ p, long long n) {
    long long i = (long long)blockIdx.x * 256 + threadIdx.x;
    if (i < n) p[i] = 0;
}

// ---------------- positional embedding ----------------
__global__ void posemb_kernel(float* __restrict__ pos) {
    int idx = blockIdx.x * 256 + threadIdx.x;
    if (idx >= S_ * D_) return;
    int s = idx / D_, d = idx % D_;
    float jj = (float)(d & ~1);
    float freq = powf(10000.0f, jj / (float)D_);
    float arg = (float)s / freq;
    pos[idx] = (d & 1) ? cosf(arg) : sinf(arg);
}

// ---------------- patchify (bf16 hi/lo) ----------------
__global__ void patchify_split_kernel(const float* __restrict__ x,
                                      u16* __restrict__ phi, u16* __restrict__ plo) {
    int idx = blockIdx.x * 256 + threadIdx.x;
    if (idx >= B_ * NP_ * NP_ * 768) return;
    int k = idx % 768;
    int p = (idx / 768) % (NP_ * NP_);
    int n = idx / (768 * NP_ * NP_);
    int c = k >> 8;
    int rem = k & 255;
    int a = rem >> 4;
    int b = rem & 15;
    int i = p / NP_, j = p % NP_;
    float v = x[(((long long)n * C_ + c) * HW_ + (i * PS_ + a)) * HW_ + (j * PS_ + b)];
    u16 h = f2bf(v);
    phi[idx] = h;
    plo[idx] = f2bf(v - bf2f(h));
}

// ---------------- cls token + pos emb ----------------
__global__ void addpos_kernel(float* __restrict__ tok, const float* __restrict__ pos,
                              const float* __restrict__ cls) {
    int idx = blockIdx.x * 256 + threadIdx.x;
    if (idx >= B_ * S_ * D_) return;
    int r = idx % (S_ * D_);
    int s = r / D_, d = r % D_;
    if (s == 0) tok[idx] = cls[d] + pos[d];
    else tok[idx] += pos[r];
}

// ---------------- layernorm -> bf16 hi/lo ----------------
__global__ __launch_bounds__(256) void ln_split_kernel(const float* __restrict__ x,
                                                       u16* __restrict__ yhi, u16* __restrict__ ylo,
                                                       const float* __restrict__ g, const float* __restrict__ b) {
    int row = blockIdx.x;
    const float* xr = x + (long long)row * D_;
    u16* yh = yhi + (long long)row * D_;
    u16* yl = ylo + (long long)row * D_;
    int tid = threadIdx.x;
    float v[3];
    float s = 0.f;
#pragma unroll
    for (int u = 0; u < 3; ++u) { v[u] = xr[tid + 256 * u]; s += v[u]; }
    __shared__ float red[256];
    red[tid] = s; __syncthreads();
    for (int off = 128; off > 0; off >>= 1) { if (tid < off) red[tid] += red[tid + off]; __syncthreads(); }
    float mu = red[0] * (1.0f / D_);
    __syncthreads();
    float s2 = 0.f;
#pragma unroll
    for (int u = 0; u < 3; ++u) { float d = v[u] - mu; s2 += d * d; }
    red[tid] = s2; __syncthreads();
    for (int off = 128; off > 0; off >>= 1) { if (tid < off) red[tid] += red[tid + off]; __syncthreads(); }
    float rstd = rsqrtf(red[0] * (1.0f / D_) + 1e-5f);
#pragma unroll
    for (int u = 0; u < 3; ++u) {
        int d = tid + 256 * u;
        float yv = (v[u] - mu) * rstd * g[d] + b[d];
        u16 h = f2bf(yv);
        yh[d] = h;
        yl[d] = f2bf(yv - bf2f(h));
    }
}

// ---------------- in-place softmax: fp32 row -> bf16 hi[224]+lo[224] ----------
__global__ __launch_bounds__(64) void att_softmax_kernel(float* __restrict__ SC) {
    long long row = blockIdx.x;
    float* p = SC + row * SP_;
    int tid = threadIdx.x;
    float v[4];
    float mx = -1e30f;
#pragma unroll
    for (int u = 0; u < 4; ++u) {
        int t = tid + 64 * u;
        v[u] = (t < S_) ? p[t] : -1e30f;
        mx = fmaxf(mx, v[u]);
    }
    for (int off = 32; off > 0; off >>= 1) mx = fmaxf(mx, __shfl_xor(mx, off));
    float sum = 0.f;
#pragma unroll
    for (int u = 0; u < 4; ++u) { v[u] = expf(v[u] - mx); sum += v[u]; }
    for (int off = 32; off > 0; off >>= 1) sum += __shfl_xor(sum, off);
    float inv = 1.0f / sum;
    u16* o = (u16*)p;
#pragma unroll
    for (int u = 0; u < 4; ++u) {
        int t = tid + 64 * u;
        if (t < SP_) {
            float pv = (t < S_) ? v[u] * inv : 0.f;
            u16 h = f2bf(pv);
            o[t] = h;
            o[SP_ + t] = f2bf(pv - bf2f(h));
        }
    }
}

// ---------------- head GEMM (fp32, tiny) ----------------
__global__ __launch_bounds__(256) void head_gemm_kernel(const float* __restrict__ tok,
                                                        const float* __restrict__ Wh,
                                                        const float* __restrict__ bh,
                                                        float* __restrict__ logits) {
    int n = blockIdx.x * 64 + (threadIdx.x & 63);
    int mg = threadIdx.x >> 6;
    if (n >= OUT_) return;
    for (int m = mg * 8; m < mg * 8 + 8; ++m) {
        const float* a = tok + (long long)m * S_ * D_;
        float acc = 0.f;
        for (int k = 0; k < D_; ++k) acc += a[k] * Wh[(long long)k * OUT_ + n];
        logits[(long long)m * OUT_ + n] = acc + bh[n];
    }
}

// ---------------- head softmax ----------------
__global__ __launch_bounds__(256) void head_softmax_kernel(const float* __restrict__ logits,
                                                           float* __restrict__ out) {
    int n = blockIdx.x;
    const float* p = logits + (long long)n * OUT_;
    int tid = threadIdx.x;
    float v[4];
    float mx = -1e30f;
#pragma unroll
    for (int u = 0; u < 4; ++u) {
        int idx = tid + 256 * u;
        v[u] = (idx < OUT_) ? p[idx] : -1e30f;
        mx = fmaxf(mx, v[u]);
    }
    __shared__ float red[256];
    red[tid] = mx; __syncthreads();
    for (int off = 128; off > 0; off >>= 1) { if (tid < off) red[tid] = fmaxf(red[tid], red[tid + off]); __syncthreads(); }
    mx = red[0];
    __syncthreads();
    float sum = 0.f;
#pragma unroll
    for (int u = 0; u < 4; ++u) { v[u] = expf(v[u] - mx); sum += v[u]; }
    red[tid] = sum; __syncthreads();
    for (int off = 128; off > 0; off >>= 1) { if (tid < off) red[tid] += red[tid + off]; __syncthreads(); }
    float inv = 1.0f / red[0];
#pragma unroll
    for (int u = 0; u < 4; ++u) {
        int idx = tid + 256 * u;
        if (idx < OUT_) out[(long long)n * OUT_ + idx] = v[u] * inv;
    }
}

// ---------------- host ----------------
static inline GP gp_base() { GP p; memset(&p, 0, sizeof(p)); p.zdiv = 1; return p; }

extern "C" void kernel_launch(void* const* d_in, const int* in_sizes, int n_in,
                              void* d_out, int out_size, void* d_ws, size_t ws_size,
                              hipStream_t stream) {
    (void)in_sizes; (void)n_in; (void)out_size; (void)ws_size;
    const float* x        = (const float*)d_in[0];
    const float* w_embed  = (const float*)d_in[1];
    const float* b_embed  = (const float*)d_in[2];
    const float* cls_tok  = (const float*)d_in[3];
    const float* ln1_g    = (const float*)d_in[4];
    const float* ln1_b    = (const float*)d_in[5];
    const float* wq       = (const float*)d_in[6];
    const float* bq       = (const float*)d_in[7];
    const float* wk       = (const float*)d_in[8];
    const float* bk       = (const float*)d_in[9];
    const float* wv       = (const float*)d_in[10];
    const float* bv       = (const float*)d_in[11];
    const float* ln2_g    = (const float*)d_in[12];
    const float* ln2_b    = (const float*)d_in[13];
    const float* w1       = (const float*)d_in[14];
    const float* b1       = (const float*)d_in[15];
    const float* w2       = (const float*)d_in[16];
    const float* b2       = (const float*)d_in[17];
    const float* w_head   = (const float*)d_in[18];
    const float* b_head   = (const float*)d_in[19];
    float* out = (float*)d_out;
    char* wsb  = (char*)d_ws;

    const long long TOKSZ = (long long)B_ * S_ * D_;   // 4,841,472
    const int M_TOK = B_ * S_;                          // 6304
    const int M_PAT = B_ * NP_ * NP_;                   // 6272
    const int NBH = B_ * NH_;                           // 384

    auto alloc = [&](long long bytes) {
        char* p = wsb;
        wsb += (bytes + 255) & ~255LL;
        return p;
    };
    float* pos    = (float*)alloc((long long)S_ * D_ * 4);
    float* tok    = (float*)alloc(TOKSZ * 4);
    u16*   h_hi   = (u16*)alloc(TOKSZ * 2);
    u16*   h_lo   = (u16*)alloc(TOKSZ * 2);
    u16*   q_hi   = (u16*)alloc(TOKSZ * 2);
    u16*   q_lo   = (u16*)alloc(TOKSZ * 2);
    u16*   k_hi   = (u16*)alloc(TOKSZ * 2);
    u16*   k_lo   = (u16*)alloc(TOKSZ * 2);
    u16*   vt_hi  = (u16*)alloc((long long)NBH * 64 * SP_ * 2);
    u16*   vt_lo  = (u16*)alloc((long long)NBH * 64 * SP_ * 2);
    u16*   wc_hi  = (u16*)alloc((long long)L_ * NH_ * 192 * 64 * 2);
    u16*   wc_lo  = (u16*)alloc((long long)L_ * NH_ * 192 * 64 * 2);
    u16*   w1t_hi = (u16*)alloc((long long)MLP_ * D_ * 2);
    u16*   w1t_lo = (u16*)alloc((long long)MLP_ * D_ * 2);
    u16*   w2t_hi = (u16*)alloc((long long)D_ * MLP_ * 2);
    u16*   w2t_lo = (u16*)alloc((long long)D_ * MLP_ * 2);
    char*  region1 = alloc((long long)M_TOK * MLP_ * 2 * 2);   // 77.5 MB
    float* SC     = (float*)region1;                            // [384][197][224] fp32
    u16*   g_hi   = (u16*)region1;
    u16*   g_lo   = g_hi + (long long)M_TOK * MLP_;
    u16*   p_hi   = (u16*)region1;
    u16*   p_lo   = p_hi + (long long)M_PAT * 768;
    float* logits = (float*)alloc((long long)B_ * OUT_ * 4);

    // ---- pre-loop ----
    posemb_kernel<<<(S_ * D_ + 255) / 256, 256, 0, stream>>>(pos);
    patchify_split_kernel<<<(M_PAT * 768 + 255) / 256, 256, 0, stream>>>(x, p_hi, p_lo);
    tconv_kernel<<<dim3(768 / 32, 768 / 32), 256, 0, stream>>>(w_embed, w1t_hi, w1t_lo, 768, 768);
    {
        const int TOT = L_ * NH_ * 192 * 64;
        qkvprep_kernel<<<(TOT + 255) / 256, 256, 0, stream>>>(wq, wk, wv, wc_hi, wc_lo);
    }
    {
        long long n32 = (long long)NBH * 64 * SP_ * 2 * 2 / 4;
        zero_kernel<<<(int)((n32 + 255) / 256), 256, 0, stream>>>((u32*)vt_hi, n32);
    }
    {   // embed GEMM: tok rows remapped (m -> m + m/196 + 1)
        GP p = gp_base();
        p.Ahi = p_hi; p.Alo = p_lo; p.Bhi = w1t_hi; p.Blo = w1t_lo;
        p.lda = 768; p.ldb = 768; p.M = M_PAT; p.N = D_; p.K = 768;
        p.MB = 49; p.SW = 6;
        p.mode = 0; p.C = tok; p.bias = b_embed; p.ldc = D_; p.remap = 1;
        gm<2><<<dim3(49 * 6, 1), 256, 0, stream>>>(p);
    }
    addpos_kernel<<<((int)TOKSZ + 255) / 256, 256, 0, stream>>>(tok, pos, cls_tok);

    for (int l = 0; l < L_; ++l) {
        ln_split_kernel<<<M_TOK, 256, 0, stream>>>(tok, h_hi, h_lo, ln1_g + l * D_, ln1_b + l * D_);
        {   // QKV batched per head: N = 192 = q | k | vT
            GP p = gp_base();
            p.Ahi = h_hi; p.Alo = h_lo; p.sA = 64;
            p.Bhi = wc_hi + (long long)l * NH_ * 192 * 64;
            p.Blo = wc_lo + (long long)l * NH_ * 192 * 64;
            p.sB = 192 * 64;
            p.lda = D_; p.ldb = 64; p.M = M_TOK; p.N = 192; p.K = 64;
            p.MB = 50; p.SW = 2;
            p.mode = 2;
            p.qh = q_hi; p.ql = q_lo; p.kh = k_hi; p.kl = k_lo; p.vh = vt_hi; p.vl = vt_lo;
            p.bq = bq + l * D_; p.bk = bk + l * D_; p.bv = bv + l * D_;
            gm<2><<<dim3(50 * 2, NH_), 256, 0, stream>>>(p);
        }
        {   // scores = q @ k^T (scale folded into q)
            GP p = gp_base();
            p.Ahi = q_hi; p.Alo = q_lo; p.sA = (long long)S_ * 64;
            p.Bhi = k_hi; p.Blo = k_lo; p.sB = (long long)S_ * 64;
            p.lda = 64; p.ldb = 64; p.M = S_; p.N = S_; p.K = 64;
            p.MB = 2; p.SW = 2;
            p.mode = 0; p.C = SC; p.sCo = (long long)S_ * SP_; p.zdiv = 1; p.ldc = SP_;
            gm<2><<<dim3(4, NBH), 256, 0, stream>>>(p);
        }
        att_softmax_kernel<<<NBH * S_, 64, 0, stream>>>(SC);
        {   // O = att @ v -> tok (+residual)
            GP p = gp_base();
            p.Ahi = (u16*)SC; p.Alo = (u16*)SC + SP_; p.sA = (long long)S_ * 2 * SP_;
            p.Bhi = vt_hi; p.Blo = vt_lo; p.sB = (long long)64 * SP_;
            p.lda = 2 * SP_; p.ldb = SP_; p.M = S_; p.N = 64; p.K = SP_;
            p.MB = 2; p.SW = 1;
            p.mode = 0; p.C = tok; p.zdiv = NH_;
            p.sCo = (long long)S_ * D_; p.sCi = 64; p.ldc = D_; p.accum = 1;
            gm<1><<<dim3(2, NBH), 128, 0, stream>>>(p);
        }
        ln_split_kernel<<<M_TOK, 256, 0, stream>>>(tok, h_hi, h_lo, ln2_g + l * D_, ln2_b + l * D_);
        tconv_kernel<<<dim3(MLP_ / 32, D_ / 32), 256, 0, stream>>>(
            w1 + (long long)l * D_ * MLP_, w1t_hi, w1t_lo, D_, MLP_);
        {   // MLP1: g = gelu(h @ w1 + b1) -> hi/lo (overwrites SC region; SC is dead)
            GP p = gp_base();
            p.Ahi = h_hi; p.Alo = h_lo; p.Bhi = w1t_hi; p.Blo = w1t_lo;
            p.lda = D_; p.ldb = D_; p.M = M_TOK; p.N = MLP_; p.K = D_;
            p.MB = 50; p.SW = 4;
            p.mode = 1; p.Ohi = g_hi; p.Olo = g_lo; p.ldo = MLP_;
            p.bias = b1 + (long long)l * MLP_;
            gm<2><<<dim3(50 * 24, 1), 256, 0, stream>>>(p);
        }
        tconv_kernel<<<dim3(D_ / 32, MLP_ / 32), 256, 0, stream>>>(
            w2 + (long long)l * MLP_ * D_, w2t_hi, w2t_lo, MLP_, D_);
        {   // MLP2: tok += g @ w2 + b2  (K split x4, atomicAdd)
            GP p = gp_base();
            p.Ahi = g_hi; p.Alo = g_lo; p.sA = 768;
            p.Bhi = w2t_hi; p.Blo = w2t_lo; p.sB = 768;
            p.lda = MLP_; p.ldb = MLP_; p.M = M_TOK; p.N = D_; p.K = 768;
            p.MB = 50; p.SW = 6;
            p.mode = 0; p.C = tok; p.bias = b2 + (long long)l * D_;
            p.zdiv = 4; p.ldc = D_; p.atomicf = 1; p.biasZ0 = 1;
            gm<2><<<dim3(50 * 6, 4), 256, 0, stream>>>(p);
        }
    }

    head_gemm_kernel<<<dim3((OUT_ + 63) / 64), 256, 0, stream>>>(tok, w_head, b_head, logits);
    head_softmax_kernel<<<B_, 256, 0, stream>>>(logits, out);
}

// Round 4
// 14002.068 us; speedup vs baseline: 1.2845x; 1.2845x over previous
//
#include <hip/hip_runtime.h>
#include <math.h>
#include <string.h>

// ---------------- dims ----------------
#define B_ 32
#define C_ 3
#define HW_ 224
#define NP_ 14
#define PS_ 16
#define S_ 197        // NP*NP + 1
#define D_ 768
#define NH_ 12
#define DH_ 64
#define L_ 12
#define MLP_ 3072
#define OUT_ 1000
#define SP_ 224       // S padded to mult of 32

typedef unsigned short u16;
typedef unsigned int u32;
typedef __attribute__((ext_vector_type(8))) short short8_t;
typedef __attribute__((ext_vector_type(4))) float f32x4;
typedef const __attribute__((address_space(1))) u16 gq_t;
typedef __attribute__((address_space(3))) u16 lq_t;

// ---------------- bf16 helpers ----------------
__device__ __forceinline__ u16 f2bf(float x) {
    union { float f; u32 u; } a; a.f = x;
    u32 r = (a.u + 0x7fffu + ((a.u >> 16) & 1u)) >> 16;   // RNE
    return (u16)r;
}
__device__ __forceinline__ float bf2f(u16 h) {
    union { u32 u; float f; } a; a.u = ((u32)h) << 16; return a.f;
}

// ================= universal bf16x3 split MFMA GEMM =================
// C = A(M x K, hi/lo bf16) @ B^T (B stored [N,K], hi/lo bf16), fp32 acc.
// 3 MFMAs per product: AhBh + AhBl + AlBh. Double-buffered LDS staging via
// global_load_lds(16B). XCD-slab block mapping for L2 locality.
struct GP {
    const u16 *Ahi, *Alo, *Bhi, *Blo;
    long long sA, sB;          // batch strides (elements)
    int lda, ldb, M, N, K;
    int MB, NB, VM;            // m-blocks, n-blocks, m-blocks per xcd slab
    int ord;                   // 0: xcd mi-inner, 1: xcd nb-inner, 2: plain linear
    int mode;                  // 0: fp32 out, 1: gelu->hi/lo, 2: qkv scatter
    float* C; const float* bias; long long sCo, sCi; int zdiv, ldc, accum, remap;
    u16 *Ohi, *Olo; int ldo;
    u16 *qh, *ql, *kh, *kl, *vh, *vl; const float *bq, *bk, *bv;
};

template<int WN>   // WN: waves along N (2 -> 128x128 tile/256t, 1 -> 128x64/128t)
__global__ __launch_bounds__(WN * 128) void gm(GP p)
{
    const int TN = 64 * WN;
    __shared__ u16 ldsA[2][2][4][128][8];   // [buf][hi/lo][k-octet][row][8]
    __shared__ u16 ldsB[2][2][4][TN][8];

    int tid = threadIdx.x;
    int lane = tid & 63;
    int w = tid >> 6;
    int wm, wn;
    if (WN == 2) { wm = (w >> 1) * 64; wn = (w & 1) * 64; }
    else         { wm = w * 64;        wn = 0; }
    int z = blockIdx.y;

    // ---- block mapping ----
    int lin = blockIdx.x;
    int m_blk, n_blk;
    if (p.ord == 2) {
        m_blk = lin / p.NB; n_blk = lin % p.NB;
    } else {
        int xcd = lin & 7, idx = lin >> 3;
        int mi, nb;
        if (p.ord == 0) { mi = idx % p.VM; nb = idx / p.VM; }
        else            { nb = idx % p.NB; mi = idx / p.NB; }
        m_blk = mi * 8 + xcd;      // interleaved slabs: balanced, <=VM panels/XCD
        n_blk = nb;
        if (m_blk >= p.MB) return;
    }
    int m0 = m_blk * 128, n0 = n_blk * TN;

    const u16* Ah = p.Ahi + (long long)z * p.sA;
    const u16* Al = p.Alo + (long long)z * p.sA;
    const u16* Bh = p.Bhi + (long long)z * p.sB;
    const u16* Bl = p.Blo + (long long)z * p.sB;

    int lm = lane & 15, qd = lane >> 4;

    const int nA = 16;
    const int nB = 8 * WN;
    const int W = 2 * WN;
    const int perW = (nA + nB) / W;

    auto stage = [&](int buf, int k0) {
#pragma unroll
        for (int t0 = 0; t0 < perW; ++t0) {
            int t = w * perW + t0;
            const u16* src; u16* dst;
            if (t < nA) {
                int mat = t >> 3, rem = t & 7, q = rem >> 1, h = rem & 1;
                int r = m0 + h * 64 + lane;
                r = r < p.M ? r : p.M - 1;
                src = (mat ? Al : Ah) + (long long)r * p.lda + (k0 + q * 8);
                dst = &ldsA[buf][mat][q][h * 64 + lane][0];
            } else {
                int tb = t - nA, mat, q, h;
                if (WN == 2) { mat = tb >> 3; int rem = tb & 7; q = rem >> 1; h = rem & 1; }
                else         { mat = tb >> 2; q = tb & 3; h = 0; }
                int r = n0 + h * 64 + lane;
                r = r < p.N ? r : p.N - 1;
                src = (mat ? Bl : Bh) + (long long)r * p.ldb + (k0 + q * 8);
                dst = &ldsB[buf][mat][q][h * 64 + lane][0];
            }
            __builtin_amdgcn_global_load_lds((gq_t*)src, (lq_t*)dst, 16, 0, 0);
        }
    };

    f32x4 acc[4][4];
#pragma unroll
    for (int i = 0; i < 4; ++i)
#pragma unroll
        for (int j = 0; j < 4; ++j)
            acc[i][j] = (f32x4){0.f, 0.f, 0.f, 0.f};

    int nc = p.K >> 5;
    stage(0, 0);
    for (int c = 0; c < nc; ++c) {
        __syncthreads();                       // drains loads into buf c&1
        if (c + 1 < nc) stage((c + 1) & 1, (c + 1) * 32);
        int buf = c & 1;
        short8_t ah[4], al[4], bh[4], bl[4];
#pragma unroll
        for (int i = 0; i < 4; ++i) {
            ah[i] = *(const short8_t*)&ldsA[buf][0][qd][wm + i * 16 + lm][0];
            al[i] = *(const short8_t*)&ldsA[buf][1][qd][wm + i * 16 + lm][0];
            bh[i] = *(const short8_t*)&ldsB[buf][0][qd][wn + i * 16 + lm][0];
            bl[i] = *(const short8_t*)&ldsB[buf][1][qd][wn + i * 16 + lm][0];
        }
#pragma unroll
        for (int i = 0; i < 4; ++i)
#pragma unroll
            for (int j = 0; j < 4; ++j) {
                acc[i][j] = __builtin_amdgcn_mfma_f32_16x16x32_bf16(ah[i], bh[j], acc[i][j], 0, 0, 0);
                acc[i][j] = __builtin_amdgcn_mfma_f32_16x16x32_bf16(ah[i], bl[j], acc[i][j], 0, 0, 0);
                acc[i][j] = __builtin_amdgcn_mfma_f32_16x16x32_bf16(al[i], bh[j], acc[i][j], 0, 0, 0);
            }
    }

    // ---- epilogue: C/D layout col=lane&15, row=quad*4+reg ----
#pragma unroll
    for (int j = 0; j < 4; ++j) {
        int gn = n0 + wn + j * 16 + lm;
        if (gn >= p.N) continue;
#pragma unroll
        for (int i = 0; i < 4; ++i) {
#pragma unroll
            for (int r = 0; r < 4; ++r) {
                int gmr = m0 + wm + i * 16 + qd * 4 + r;
                if (gmr >= p.M) continue;
                float v = acc[i][j][r];
                if (p.mode == 0) {
                    if (p.bias) v += p.bias[gn];
                    int orow = p.remap ? (gmr + gmr / 196 + 1) : gmr;
                    long long idx = (long long)(z / p.zdiv) * p.sCo + (long long)(z % p.zdiv) * p.sCi
                                  + (long long)orow * p.ldc + gn;
                    if (p.accum) v += p.C[idx];
                    p.C[idx] = v;
                } else if (p.mode == 1) {
                    v += p.bias[gn];
                    v = 0.5f * v * (1.0f + erff(v * 0.70710678118654752f));
                    u16 h = f2bf(v);
                    long long idx = (long long)gmr * p.ldo + gn;
                    p.Ohi[idx] = h;
                    p.Olo[idx] = f2bf(v - bf2f(h));
                } else {
                    int b = gmr / S_, s = gmr - b * S_;
                    if (gn < 64) {
                        float val = (v + p.bq[z * 64 + gn]) * 0.125f;
                        long long idx = ((long long)(b * NH_ + z) * S_ + s) * 64 + gn;
                        u16 h = f2bf(val);
                        p.qh[idx] = h; p.ql[idx] = f2bf(val - bf2f(h));
                    } else if (gn < 128) {
                        int e = gn - 64;
                        float val = v + p.bk[z * 64 + e];
                        long long idx = ((long long)(b * NH_ + z) * S_ + s) * 64 + e;
                        u16 h = f2bf(val);
                        p.kh[idx] = h; p.kl[idx] = f2bf(val - bf2f(h));
                    } else {
                        int e = gn - 128;
                        float val = v + p.bv[z * 64 + e];
                        long long idx = ((long long)(b * NH_ + z) * S_ + s) * 64 + e;  // natural layout
                        u16 h = f2bf(val);
                        p.vh[idx] = h; p.vl[idx] = f2bf(val - bf2f(h));
                    }
                }
            }
        }
    }
}

// ---------------- V transpose: v[z][s][e] -> vt[z][e][sp] (pads s>=197 w/ 0) --
__global__ __launch_bounds__(256) void vtrans_kernel(const u16* __restrict__ vhi,
                                                     const u16* __restrict__ vlo,
                                                     u16* __restrict__ vthi,
                                                     u16* __restrict__ vtlo) {
    __shared__ u16 t[64][66];
    int z = blockIdx.y;
    const u16* src = blockIdx.z ? vlo : vhi;
    u16* dst = blockIdx.z ? vtlo : vthi;
    int s0 = blockIdx.x * 64;
    int tq = threadIdx.x >> 6;     // 0..3
    int e = threadIdx.x & 63;
#pragma unroll
    for (int i = 0; i < 16; ++i) {
        int sl = tq * 16 + i;
        int s = s0 + sl;
        t[sl][e] = (s < S_) ? src[((long long)z * S_ + s) * 64 + e] : (u16)0;
    }
    __syncthreads();
    int sl = threadIdx.x & 63;
    int s = s0 + sl;
    if (s < SP_) {
#pragma unroll
        for (int i = 0; i < 16; ++i) {
            int ee = tq * 16 + i;
            dst[((long long)z * 64 + ee) * SP_ + s] = t[sl][ee];
        }
    }
}

// ---------------- transpose + hi/lo split: W[K][N] -> T[N][K] ----------------
__global__ __launch_bounds__(256) void tconv_kernel(const float* __restrict__ W,
                                                    u16* __restrict__ Thi, u16* __restrict__ Tlo,
                                                    int K, int N)
{
    __shared__ float t[32][33];
    int n0 = blockIdx.x * 32, k0 = blockIdx.y * 32;
    int tc = threadIdx.x & 31, tr = threadIdx.x >> 5;
#pragma unroll
    for (int u = 0; u < 4; ++u) {
        int kk = tr + u * 8;
        t[kk][tc] = W[(long long)(k0 + kk) * N + n0 + tc];
    }
    __syncthreads();
#pragma unroll
    for (int u = 0; u < 4; ++u) {
        int nn = tr + u * 8;
        float v = t[tc][nn];
        u16 h = f2bf(v);
        long long idx = (long long)(n0 + nn) * K + k0 + tc;
        Thi[idx] = h;
        Tlo[idx] = f2bf(v - bf2f(h));
    }
}

// ---------------- QKV weight prep: Wcat[l][h][p*64+e][d] = w_p[l][h][d][e] ----
__global__ void qkvprep_kernel(const float* __restrict__ wq, const float* __restrict__ wk,
                               const float* __restrict__ wv,
                               u16* __restrict__ Whi, u16* __restrict__ Wlo) {
    int idx = blockIdx.x * 256 + threadIdx.x;
    const int TOT = L_ * NH_ * 192 * 64;
    if (idx >= TOT) return;
    int d = idx & 63;
    int r = (idx >> 6) % 192;
    int h = (idx >> 6) / 192 % NH_;
    int l = idx / (192 * 64 * NH_);
    int pg = r >> 6, e = r & 63;
    const float* W = pg == 0 ? wq : pg == 1 ? wk : wv;
    float v = W[(((long long)l * NH_ + h) * 64 + d) * 64 + e];
    u16 hh = f2bf(v);
    Whi[idx] = hh;
    Wlo[idx] = f2bf(v - bf2f(hh));
}

// ---------------- positional embedding ----------------
__global__ void posemb_kernel(float* __restrict__ pos) {
    int idx = blockIdx.x * 256 + threadIdx.x;
    if (idx >= S_ * D_) return;
    int s = idx / D_, d = idx % D_;
    float jj = (float)(d & ~1);
    float freq = powf(10000.0f, jj / (float)D_);
    float arg = (float)s / freq;
    pos[idx] = (d & 1) ? cosf(arg) : sinf(arg);
}

// ---------------- patchify (bf16 hi/lo) ----------------
__global__ void patchify_split_kernel(const float* __restrict__ x,
                                      u16* __restrict__ phi, u16* __restrict__ plo) {
    int idx = blockIdx.x * 256 + threadIdx.x;
    if (idx >= B_ * NP_ * NP_ * 768) return;
    int k = idx % 768;
    int p = (idx / 768) % (NP_ * NP_);
    int n = idx / (768 * NP_ * NP_);
    int c = k >> 8;
    int rem = k & 255;
    int a = rem >> 4;
    int b = rem & 15;
    int i = p / NP_, j = p % NP_;
    float v = x[(((long long)n * C_ + c) * HW_ + (i * PS_ + a)) * HW_ + (j * PS_ + b)];
    u16 h = f2bf(v);
    phi[idx] = h;
    plo[idx] = f2bf(v - bf2f(h));
}

// ---------------- cls token + pos emb ----------------
__global__ void addpos_kernel(float* __restrict__ tok, const float* __restrict__ pos,
                              const float* __restrict__ cls) {
    int idx = blockIdx.x * 256 + threadIdx.x;
    if (idx >= B_ * S_ * D_) return;
    int r = idx % (S_ * D_);
    int s = r / D_, d = r % D_;
    if (s == 0) tok[idx] = cls[d] + pos[d];
    else tok[idx] += pos[r];
}

// ---------------- layernorm -> bf16 hi/lo ----------------
__global__ __launch_bounds__(256) void ln_split_kernel(const float* __restrict__ x,
                                                       u16* __restrict__ yhi, u16* __restrict__ ylo,
                                                       const float* __restrict__ g, const float* __restrict__ b) {
    int row = blockIdx.x;
    const float* xr = x + (long long)row * D_;
    u16* yh = yhi + (long long)row * D_;
    u16* yl = ylo + (long long)row * D_;
    int tid = threadIdx.x;
    float v[3];
    float s = 0.f;
#pragma unroll
    for (int u = 0; u < 3; ++u) { v[u] = xr[tid + 256 * u]; s += v[u]; }
    __shared__ float red[256];
    red[tid] = s; __syncthreads();
    for (int off = 128; off > 0; off >>= 1) { if (tid < off) red[tid] += red[tid + off]; __syncthreads(); }
    float mu = red[0] * (1.0f / D_);
    __syncthreads();
    float s2 = 0.f;
#pragma unroll
    for (int u = 0; u < 3; ++u) { float d = v[u] - mu; s2 += d * d; }
    red[tid] = s2; __syncthreads();
    for (int off = 128; off > 0; off >>= 1) { if (tid < off) red[tid] += red[tid + off]; __syncthreads(); }
    float rstd = rsqrtf(red[0] * (1.0f / D_) + 1e-5f);
#pragma unroll
    for (int u = 0; u < 3; ++u) {
        int d = tid + 256 * u;
        float yv = (v[u] - mu) * rstd * g[d] + b[d];
        u16 h = f2bf(yv);
        yh[d] = h;
        yl[d] = f2bf(yv - bf2f(h));
    }
}

// ---------------- in-place softmax: fp32 row -> bf16 hi[224]+lo[224] ----------
__global__ __launch_bounds__(64) void att_softmax_kernel(float* __restrict__ SC) {
    long long row = blockIdx.x;
    float* p = SC + row * SP_;
    int tid = threadIdx.x;
    float v[4];
    float mx = -1e30f;
#pragma unroll
    for (int u = 0; u < 4; ++u) {
        int t = tid + 64 * u;
        v[u] = (t < S_) ? p[t] : -1e30f;
        mx = fmaxf(mx, v[u]);
    }
    for (int off = 32; off > 0; off >>= 1) mx = fmaxf(mx, __shfl_xor(mx, off));
    float sum = 0.f;
#pragma unroll
    for (int u = 0; u < 4; ++u) { v[u] = expf(v[u] - mx); sum += v[u]; }
    for (int off = 32; off > 0; off >>= 1) sum += __shfl_xor(sum, off);
    float inv = 1.0f / sum;
    u16* o = (u16*)p;
#pragma unroll
    for (int u = 0; u < 4; ++u) {
        int t = tid + 64 * u;
        if (t < SP_) {
            float pv = (t < S_) ? v[u] * inv : 0.f;
            u16 h = f2bf(pv);
            o[t] = h;
            o[SP_ + t] = f2bf(pv - bf2f(h));
        }
    }
}

// ---------------- head GEMM (fp32, tiny) ----------------
__global__ __launch_bounds__(256) void head_gemm_kernel(const float* __restrict__ tok,
                                                        const float* __restrict__ Wh,
                                                        const float* __restrict__ bh,
                                                        float* __restrict__ logits) {
    int n = blockIdx.x * 64 + (threadIdx.x & 63);
    int mg = threadIdx.x >> 6;
    if (n >= OUT_) return;
    for (int m = mg * 8; m < mg * 8 + 8; ++m) {
        const float* a = tok + (long long)m * S_ * D_;
        float acc = 0.f;
        for (int k = 0; k < D_; ++k) acc += a[k] * Wh[(long long)k * OUT_ + n];
        logits[(long long)m * OUT_ + n] = acc + bh[n];
    }
}

// ---------------- head softmax ----------------
__global__ __launch_bounds__(256) void head_softmax_kernel(const float* __restrict__ logits,
                                                           float* __restrict__ out) {
    int n = blockIdx.x;
    const float* p = logits + (long long)n * OUT_;
    int tid = threadIdx.x;
    float v[4];
    float mx = -1e30f;
#pragma unroll
    for (int u = 0; u < 4; ++u) {
        int idx = tid + 256 * u;
        v[u] = (idx < OUT_) ? p[idx] : -1e30f;
        mx = fmaxf(mx, v[u]);
    }
    __shared__ float red[256];
    red[tid] = mx; __syncthreads();
    for (int off = 128; off > 0; off >>= 1) { if (tid < off) red[tid] = fmaxf(red[tid], red[tid + off]); __syncthreads(); }
    mx = red[0];
    __syncthreads();
    float sum = 0.f;
#pragma unroll
    for (int u = 0; u < 4; ++u) { v[u] = expf(v[u] - mx); sum += v[u]; }
    red[tid] = sum; __syncthreads();
    for (int off = 128; off > 0; off >>= 1) { if (tid < off) red[tid] += red[tid + off]; __syncthreads(); }
    float inv = 1.0f / red[0];
#pragma unroll
    for (int u = 0; u < 4; ++u) {
        int idx = tid + 256 * u;
        if (idx < OUT_) out[(long long)n * OUT_ + idx] = v[u] * inv;
    }
}

// ---------------- host ----------------
static inline GP gp_base() { GP p; memset(&p, 0, sizeof(p)); p.zdiv = 1; return p; }

extern "C" void kernel_launch(void* const* d_in, const int* in_sizes, int n_in,
                              void* d_out, int out_size, void* d_ws, size_t ws_size,
                              hipStream_t stream) {
    (void)in_sizes; (void)n_in; (void)out_size; (void)ws_size;
    const float* x        = (const float*)d_in[0];
    const float* w_embed  = (const float*)d_in[1];
    const float* b_embed  = (const float*)d_in[2];
    const float* cls_tok  = (const float*)d_in[3];
    const float* ln1_g    = (const float*)d_in[4];
    const float* ln1_b    = (const float*)d_in[5];
    const float* wq       = (const float*)d_in[6];
    const float* bq       = (const float*)d_in[7];
    const float* wk       = (const float*)d_in[8];
    const float* bk       = (const float*)d_in[9];
    const float* wv       = (const float*)d_in[10];
    const float* bv       = (const float*)d_in[11];
    const float* ln2_g    = (const float*)d_in[12];
    const float* ln2_b    = (const float*)d_in[13];
    const float* w1       = (const float*)d_in[14];
    const float* b1       = (const float*)d_in[15];
    const float* w2       = (const float*)d_in[16];
    const float* b2       = (const float*)d_in[17];
    const float* w_head   = (const float*)d_in[18];
    const float* b_head   = (const float*)d_in[19];
    float* out = (float*)d_out;
    char* wsb  = (char*)d_ws;

    const long long TOKSZ = (long long)B_ * S_ * D_;   // 4,841,472
    const int M_TOK = B_ * S_;                          // 6304
    const int M_PAT = B_ * NP_ * NP_;                   // 6272
    const int NBH = B_ * NH_;                           // 384

    auto alloc = [&](long long bytes) {
        char* p = wsb;
        wsb += (bytes + 255) & ~255LL;
        return p;
    };
    float* pos    = (float*)alloc((long long)S_ * D_ * 4);
    float* tok    = (float*)alloc(TOKSZ * 4);
    u16*   h_hi   = (u16*)alloc(TOKSZ * 2);
    u16*   h_lo   = (u16*)alloc(TOKSZ * 2);
    u16*   q_hi   = (u16*)alloc(TOKSZ * 2);
    u16*   q_lo   = (u16*)alloc(TOKSZ * 2);
    u16*   k_hi   = (u16*)alloc(TOKSZ * 2);
    u16*   k_lo   = (u16*)alloc(TOKSZ * 2);
    u16*   v_hi   = (u16*)alloc(TOKSZ * 2);
    u16*   v_lo   = (u16*)alloc(TOKSZ * 2);
    u16*   vt_hi  = (u16*)alloc((long long)NBH * 64 * SP_ * 2);
    u16*   vt_lo  = (u16*)alloc((long long)NBH * 64 * SP_ * 2);
    u16*   wc_hi  = (u16*)alloc((long long)L_ * NH_ * 192 * 64 * 2);
    u16*   wc_lo  = (u16*)alloc((long long)L_ * NH_ * 192 * 64 * 2);
    u16*   w1t_hi = (u16*)alloc((long long)MLP_ * D_ * 2);
    u16*   w1t_lo = (u16*)alloc((long long)MLP_ * D_ * 2);
    u16*   w2t_hi = (u16*)alloc((long long)D_ * MLP_ * 2);
    u16*   w2t_lo = (u16*)alloc((long long)D_ * MLP_ * 2);
    char*  region1 = alloc((long long)M_TOK * MLP_ * 2 * 2);   // 77.5 MB
    float* SC     = (float*)region1;                            // [384][197][224] fp32
    u16*   g_hi   = (u16*)region1;
    u16*   g_lo   = g_hi + (long long)M_TOK * MLP_;
    u16*   p_hi   = (u16*)region1;
    u16*   p_lo   = p_hi + (long long)M_PAT * 768;
    float* logits = (float*)alloc((long long)B_ * OUT_ * 4);

    // ---- pre-loop ----
    posemb_kernel<<<(S_ * D_ + 255) / 256, 256, 0, stream>>>(pos);
    patchify_split_kernel<<<(M_PAT * 768 + 255) / 256, 256, 0, stream>>>(x, p_hi, p_lo);
    tconv_kernel<<<dim3(768 / 32, 768 / 32), 256, 0, stream>>>(w_embed, w1t_hi, w1t_lo, 768, 768);
    {
        const int TOT = L_ * NH_ * 192 * 64;
        qkvprep_kernel<<<(TOT + 255) / 256, 256, 0, stream>>>(wq, wk, wv, wc_hi, wc_lo);
    }
    {   // embed GEMM: tok rows remapped (m -> m + m/196 + 1)
        GP p = gp_base();
        p.Ahi = p_hi; p.Alo = p_lo; p.Bhi = w1t_hi; p.Blo = w1t_lo;
        p.lda = 768; p.ldb = 768; p.M = M_PAT; p.N = D_; p.K = 768;
        p.MB = 49; p.NB = 6; p.VM = 7; p.ord = 0;
        p.mode = 0; p.C = tok; p.bias = b_embed; p.ldc = D_; p.remap = 1;
        gm<2><<<dim3(8 * 7 * 6, 1), 256, 0, stream>>>(p);
    }
    addpos_kernel<<<((int)TOKSZ + 255) / 256, 256, 0, stream>>>(tok, pos, cls_tok);

    for (int l = 0; l < L_; ++l) {
        ln_split_kernel<<<M_TOK, 256, 0, stream>>>(tok, h_hi, h_lo, ln1_g + l * D_, ln1_b + l * D_);
        {   // QKV batched per head: N = 192 = q | k | v
            GP p = gp_base();
            p.Ahi = h_hi; p.Alo = h_lo; p.sA = 64;
            p.Bhi = wc_hi + (long long)l * NH_ * 192 * 64;
            p.Blo = wc_lo + (long long)l * NH_ * 192 * 64;
            p.sB = 192 * 64;
            p.lda = D_; p.ldb = 64; p.M = M_TOK; p.N = 192; p.K = 64;
            p.MB = 50; p.NB = 2; p.VM = 7; p.ord = 0;
            p.mode = 2;
            p.qh = q_hi; p.ql = q_lo; p.kh = k_hi; p.kl = k_lo; p.vh = v_hi; p.vl = v_lo;
            p.bq = bq + l * D_; p.bk = bk + l * D_; p.bv = bv + l * D_;
            gm<2><<<dim3(8 * 7 * 2, NH_), 256, 0, stream>>>(p);
        }
        // v[z][s][e] -> vt[z][e][sp] (also zero-fills the s-padding)
        vtrans_kernel<<<dim3(4, NBH, 2), 256, 0, stream>>>(v_hi, v_lo, vt_hi, vt_lo);
        {   // scores = q @ k^T (scale folded into q)
            GP p = gp_base();
            p.Ahi = q_hi; p.Alo = q_lo; p.sA = (long long)S_ * 64;
            p.Bhi = k_hi; p.Blo = k_lo; p.sB = (long long)S_ * 64;
            p.lda = 64; p.ldb = 64; p.M = S_; p.N = S_; p.K = 64;
            p.MB = 2; p.NB = 2; p.VM = 1; p.ord = 2;
            p.mode = 0; p.C = SC; p.sCo = (long long)S_ * SP_; p.zdiv = 1; p.ldc = SP_;
            gm<2><<<dim3(4, NBH), 256, 0, stream>>>(p);
        }
        att_softmax_kernel<<<NBH * S_, 64, 0, stream>>>(SC);
        {   // O = att @ v -> tok (+residual)
            GP p = gp_base();
            p.Ahi = (u16*)SC; p.Alo = (u16*)SC + SP_; p.sA = (long long)S_ * 2 * SP_;
            p.Bhi = vt_hi; p.Blo = vt_lo; p.sB = (long long)64 * SP_;
            p.lda = 2 * SP_; p.ldb = SP_; p.M = S_; p.N = 64; p.K = SP_;
            p.MB = 2; p.NB = 1; p.VM = 1; p.ord = 2;
            p.mode = 0; p.C = tok; p.zdiv = NH_;
            p.sCo = (long long)S_ * D_; p.sCi = 64; p.ldc = D_; p.accum = 1;
            gm<1><<<dim3(2, NBH), 128, 0, stream>>>(p);
        }
        ln_split_kernel<<<M_TOK, 256, 0, stream>>>(tok, h_hi, h_lo, ln2_g + l * D_, ln2_b + l * D_);
        tconv_kernel<<<dim3(MLP_ / 32, D_ / 32), 256, 0, stream>>>(
            w1 + (long long)l * D_ * MLP_, w1t_hi, w1t_lo, D_, MLP_);
        {   // MLP1: g = gelu(h @ w1 + b1) -> hi/lo (SC region is dead here)
            GP p = gp_base();
            p.Ahi = h_hi; p.Alo = h_lo; p.Bhi = w1t_hi; p.Blo = w1t_lo;
            p.lda = D_; p.ldb = D_; p.M = M_TOK; p.N = MLP_; p.K = D_;
            p.MB = 50; p.NB = 24; p.VM = 7; p.ord = 0;
            p.mode = 1; p.Ohi = g_hi; p.Olo = g_lo; p.ldo = MLP_;
            p.bias = b1 + (long long)l * MLP_;
            gm<2><<<dim3(8 * 7 * 24, 1), 256, 0, stream>>>(p);
        }
        tconv_kernel<<<dim3(D_ / 32, MLP_ / 32), 256, 0, stream>>>(
            w2 + (long long)l * MLP_ * D_, w2t_hi, w2t_lo, MLP_, D_);
        {   // MLP2: tok += g @ w2 + b2 (single pass, nb-inner so n-blocks share A panels)
            GP p = gp_base();
            p.Ahi = g_hi; p.Alo = g_lo;
            p.Bhi = w2t_hi; p.Blo = w2t_lo;
            p.lda = MLP_; p.ldb = MLP_; p.M = M_TOK; p.N = D_; p.K = MLP_;
            p.MB = 50; p.NB = 6; p.VM = 7; p.ord = 1;
            p.mode = 0; p.C = tok; p.bias = b2 + (long long)l * D_;
            p.ldc = D_; p.accum = 1;
            gm<2><<<dim3(8 * 7 * 6, 1), 256, 0, stream>>>(p);
        }
    }

    head_gemm_kernel<<<dim3((OUT_ + 63) / 64), 256, 0, stream>>>(tok, w_head, b_head, logits);
    head_softmax_kernel<<<B_, 256, 0, stream>>>(logits, out);
}